// Round 9
// baseline (2748.831 us; speedup 1.0000x reference)
//
#include <hip/hip_runtime.h>
#include <hip/hip_bf16.h>
#include <math.h>

// Problem dims
#define NB 16
#define NS 256
#define ND 512
#define NH 1024
#define NF 2048
#define NHID 256

typedef __attribute__((ext_vector_type(8))) short bf16x8;
typedef __attribute__((ext_vector_type(4))) float f32x4;

__device__ __forceinline__ unsigned short f2bf(float f) {
    unsigned u = __float_as_uint(f);
    unsigned r = u + 0x7fffu + ((u >> 16) & 1u);
    return (unsigned short)(r >> 16);
}
__device__ __forceinline__ float bf2f(unsigned short h) {
    return __uint_as_float(((unsigned)h) << 16);
}

// ---------------------------------------------------------------------------
// Split-bf16 MFMA GEMM v3: C[M,N] = A[M,K] @ B[N,K]^T (+bias)(+gelu)
// Pre-split hi/lo bf16 operands, 3-pass (Ah*Bh + Al*Bh + Ah*Bl ~ fp32).
// lda/ldb: row strides in u16 elems. global_load_lds width-16 staging,
// linear LDS (m97 structure). Tile 128x128, BK=32, 256 thr. Z-batched.
// ---------------------------------------------------------------------------
template<int ACT, int OUT_SPLIT>
__global__ __launch_bounds__(256) void sgemm3(
    const unsigned short* __restrict__ Ahi, const unsigned short* __restrict__ Alo,
    const unsigned short* __restrict__ Bhi, const unsigned short* __restrict__ Blo,
    const float* __restrict__ bias,
    float* __restrict__ C, unsigned short* __restrict__ Chi, unsigned short* __restrict__ Clo,
    int M, int N, int K, int lda, int ldb, long sA, long sB, long sC)
{
    __shared__ unsigned short Ah[128 * 32];
    __shared__ unsigned short Al[128 * 32];
    __shared__ unsigned short Bh[128 * 32];
    __shared__ unsigned short Bl[128 * 32];

    const int t = threadIdx.x;
    const int z = blockIdx.z;
    const int m0 = blockIdx.y * 128, n0 = blockIdx.x * 128;
    const int wid = t >> 6, lane = t & 63;
    const int wr = (wid >> 1) * 64, wc = (wid & 1) * 64;
    const int lr = lane & 15, lk = lane >> 4;
    const int rl = lane >> 2, sl = lane & 3;

    const unsigned short* pAh = Ahi + (size_t)z * sA;
    const unsigned short* pAl = Alo + (size_t)z * sA;
    const unsigned short* pBh = Bhi + (size_t)z * sB;
    const unsigned short* pBl = Blo + (size_t)z * sB;

    f32x4 acc[4][4];
    #pragma unroll
    for (int i = 0; i < 4; ++i)
        #pragma unroll
        for (int j = 0; j < 4; ++j) acc[i][j] = (f32x4){0.f, 0.f, 0.f, 0.f};

    for (int k0 = 0; k0 < K; k0 += 32) {
        #pragma unroll
        for (int e = 0; e < 2; ++e) {
            const int r = e * 64 + wid * 16 + rl;
            const size_t goA = (size_t)(m0 + r) * lda + k0 + sl * 8;
            const size_t goB = (size_t)(n0 + r) * ldb + k0 + sl * 8;
            const int lo = (e * 64 + wid * 16) * 32;
            __builtin_amdgcn_global_load_lds((const void*)(pAh + goA), (void*)&Ah[lo], 16, 0, 0);
            __builtin_amdgcn_global_load_lds((const void*)(pAl + goA), (void*)&Al[lo], 16, 0, 0);
            __builtin_amdgcn_global_load_lds((const void*)(pBh + goB), (void*)&Bh[lo], 16, 0, 0);
            __builtin_amdgcn_global_load_lds((const void*)(pBl + goB), (void*)&Bl[lo], 16, 0, 0);
        }
        __syncthreads();

        bf16x8 ah[4], al[4], bh[4], bl[4];
        #pragma unroll
        for (int mt = 0; mt < 4; ++mt) {
            int rf = wr + mt * 16 + lr;
            ah[mt] = *(const bf16x8*)&Ah[rf * 32 + lk * 8];
            al[mt] = *(const bf16x8*)&Al[rf * 32 + lk * 8];
        }
        #pragma unroll
        for (int nt = 0; nt < 4; ++nt) {
            int rf = wc + nt * 16 + lr;
            bh[nt] = *(const bf16x8*)&Bh[rf * 32 + lk * 8];
            bl[nt] = *(const bf16x8*)&Bl[rf * 32 + lk * 8];
        }
        #pragma unroll
        for (int mt = 0; mt < 4; ++mt)
            #pragma unroll
            for (int nt = 0; nt < 4; ++nt) {
                acc[mt][nt] = __builtin_amdgcn_mfma_f32_16x16x32_bf16(ah[mt], bh[nt], acc[mt][nt], 0, 0, 0);
                acc[mt][nt] = __builtin_amdgcn_mfma_f32_16x16x32_bf16(al[mt], bh[nt], acc[mt][nt], 0, 0, 0);
                acc[mt][nt] = __builtin_amdgcn_mfma_f32_16x16x32_bf16(ah[mt], bl[nt], acc[mt][nt], 0, 0, 0);
            }
        __syncthreads();
    }

    #pragma unroll
    for (int nt = 0; nt < 4; ++nt) {
        int col = n0 + wc + nt * 16 + lr;
        float bv = bias ? bias[col] : 0.0f;
        #pragma unroll
        for (int mt = 0; mt < 4; ++mt) {
            #pragma unroll
            for (int i = 0; i < 4; ++i) {
                int row = m0 + wr + mt * 16 + lk * 4 + i;
                float x = acc[mt][nt][i] + bv;
                if (ACT == 1) x = 0.5f * x * (1.0f + erff(x * 0.70710678118654752f));
                size_t oi = (size_t)z * sC + (size_t)row * N + col;
                if (OUT_SPLIT) {
                    unsigned short h = f2bf(x);
                    Chi[oi] = h;
                    Clo[oi] = f2bf(x - bf2f(h));
                } else {
                    C[oi] = x;
                }
            }
        }
    }
}

static void gemm_f(int act, const unsigned short* Ahi, const unsigned short* Alo,
                   const unsigned short* Bhi, const unsigned short* Blo,
                   const float* bias, float* C, int M, int N, int K, int lda, int ldb,
                   long sA, long sB, long sC, int Z, hipStream_t st)
{
    dim3 g(N / 128, M / 128, Z), b(256);
    if (act) sgemm3<1, 0><<<g, b, 0, st>>>(Ahi, Alo, Bhi, Blo, bias, C, nullptr, nullptr, M, N, K, lda, ldb, sA, sB, sC);
    else     sgemm3<0, 0><<<g, b, 0, st>>>(Ahi, Alo, Bhi, Blo, bias, C, nullptr, nullptr, M, N, K, lda, ldb, sA, sB, sC);
}
static void gemm_s(int act, const unsigned short* Ahi, const unsigned short* Alo,
                   const unsigned short* Bhi, const unsigned short* Blo,
                   const float* bias, unsigned short* Chi, unsigned short* Clo,
                   int M, int N, int K, int lda, int ldb,
                   long sA, long sB, long sC, int Z, hipStream_t st)
{
    dim3 g(N / 128, M / 128, Z), b(256);
    if (act) sgemm3<1, 1><<<g, b, 0, st>>>(Ahi, Alo, Bhi, Blo, bias, nullptr, Chi, Clo, M, N, K, lda, ldb, sA, sB, sC);
    else     sgemm3<0, 1><<<g, b, 0, st>>>(Ahi, Alo, Bhi, Blo, bias, nullptr, Chi, Clo, M, N, K, lda, ldb, sA, sB, sC);
}

// ---------------------------------------------------------------------------
// fp32 -> split bf16 hi/lo (n multiple of 1024)
// ---------------------------------------------------------------------------
__global__ __launch_bounds__(256) void cvt_split(const float* __restrict__ in,
                                                 unsigned short* __restrict__ hi,
                                                 unsigned short* __restrict__ lo)
{
    size_t i = ((size_t)blockIdx.x * 256 + threadIdx.x) * 4;
    float4 v = *(const float4*)(in + i);
    ushort4 h, l;
    h.x = f2bf(v.x); l.x = f2bf(v.x - bf2f(h.x));
    h.y = f2bf(v.y); l.y = f2bf(v.y - bf2f(h.y));
    h.z = f2bf(v.z); l.z = f2bf(v.z - bf2f(h.z));
    h.w = f2bf(v.w); l.w = f2bf(v.w - bf2f(h.w));
    *(ushort4*)(hi + i) = h;
    *(ushort4*)(lo + i) = l;
}

// ---------------------------------------------------------------------------
// bf16 (R,C) -> (C,R) transpose, z-batched. R,C multiples of 64.
// ---------------------------------------------------------------------------
__global__ __launch_bounds__(256) void tcvt_bf16(const unsigned short* __restrict__ in,
                                                 unsigned short* __restrict__ out,
                                                 int R, int C)
{
    __shared__ unsigned short tile[64 * 72];
    int z = blockIdx.z;
    in += (size_t)z * R * C;
    out += (size_t)z * R * C;
    int r0 = blockIdx.y * 64, c0 = blockIdx.x * 64;
    int t = threadIdx.x;
    int tr = t >> 2, tc = (t & 3) * 16;

    uint4 q0 = *(const uint4*)(in + (size_t)(r0 + tr) * C + c0 + tc);
    uint4 q1 = *(const uint4*)(in + (size_t)(r0 + tr) * C + c0 + tc + 8);
    unsigned short e[16];
    *(uint4*)(e) = q0;
    *(uint4*)(e + 8) = q1;
    #pragma unroll
    for (int i = 0; i < 16; ++i) tile[(tc + i) * 72 + tr] = e[i];
    __syncthreads();

    uint4 o0 = *(const uint4*)(&tile[tr * 72 + tc]);
    uint4 o1 = *(const uint4*)(&tile[tr * 72 + tc + 8]);
    *(uint4*)(out + (size_t)(c0 + tr) * R + r0 + tc) = o0;
    *(uint4*)(out + (size_t)(c0 + tr) * R + r0 + tc + 8) = o1;
}

// ---------------------------------------------------------------------------
// bias combine
// ---------------------------------------------------------------------------
__global__ __launch_bounds__(256) void bias_sum_kernel(
    const float* bihF, const float* bhhF, const float* bihB, const float* bhhB,
    float* out)
{
    int i = blockIdx.x * 256 + threadIdx.x;
    if (i < 1024) out[i] = bihF[i] + bhhF[i];
    else out[i] = bihB[i - 1024] + bhhB[i - 1024];
}

// ---------------------------------------------------------------------------
// LSTM recurrence v8: tagged self-validating h-exchange (no flags, no fences).
// grid = 32 blocks (dir = bid>>4, slice = bid&15), block = 256 (4 waves).
// Per unit h packed as u64 {lo32: bf16hi|bf16lo, hi32: step tag si+1} stored
// via relaxed AGENT-scope atomic (8B single-copy atomic -> tag travels with
// data; no release ordering needed). Receiver issues all 16 tagged loads
// (coalesced: thread = unit, word = tid + 256*j), re-loads stale ones.
// Parity double buffer safe: seeing ALL tags == si implies every block
// finished reading buffer[(si-2)&1] (its read precedes its store).
// Weights: split hi/lo bf16 B-fragments register-resident (loaded once).
// pre layout: row (b*NS+s) x 2048, [F gates 1024 | B gates 1024].
// ---------------------------------------------------------------------------
__global__ __launch_bounds__(256) void lstm_rec8(
    const float* __restrict__ pre,
    const float* __restrict__ WhhF, const float* __restrict__ WhhB,
    unsigned long long* __restrict__ hg,   // [2 parity][2 dir][16 b][256 u] u64
    unsigned short* __restrict__ fhi, unsigned short* __restrict__ flo)
{
    const int bid = blockIdx.x;
    const int dir = bid >> 4, slice = bid & 15;
    const float* Whh = dir ? WhhB : WhhF;

    const int tid = threadIdx.x;
    const int wv = tid >> 6;            // wave = gate 0..3 (i,f,g,o)
    const int lane = tid & 63;
    const int lr = lane & 15;
    const int lk = lane >> 4;
    const int eb = tid >> 4;            // elementwise batch
    const int eu = tid & 15;            // elementwise unit-local

    __shared__ unsigned short hh[16 * 264];
    __shared__ unsigned short hl[16 * 264];
    __shared__ float gx[4][16][17];

    // one-time: weight fragments into registers (split hi/lo)
    bf16x8 wfh[8], wfl[8];
    {
        const float* wrow = Whh + (size_t)(wv * 256 + slice * 16 + lr) * 256 + lk * 8;
        #pragma unroll
        for (int kt = 0; kt < 8; ++kt) {
            float4 a = *(const float4*)(wrow + kt * 32);
            float4 b = *(const float4*)(wrow + kt * 32 + 4);
            float v[8] = {a.x, a.y, a.z, a.w, b.x, b.y, b.z, b.w};
            unsigned short hhv[8], llv[8];
            #pragma unroll
            for (int i = 0; i < 8; ++i) {
                unsigned short h = f2bf(v[i]);
                hhv[i] = h;
                llv[i] = f2bf(v[i] - bf2f(h));
            }
            wfh[kt] = *(bf16x8*)hhv;
            wfl[kt] = *(bf16x8*)llv;
        }
    }
    for (int i = tid; i < 16 * 264; i += 256) { hh[i] = 0; hl[i] = 0; }

    float c = 0.0f;
    __syncthreads();

    for (int si = 0; si < NS; ++si) {
        const int s = dir ? (NS - 1 - si) : si;
        // pre loads issued early (hide L2 latency under the poll)
        const float* pp = pre + ((size_t)(eb * NS + s)) * 2048 + dir * 1024 + slice * 16 + eu;
        float pi = pp[0], pf = pp[256], pg = pp[512], po = pp[768];

        if (si > 0) {
            // tagged h receive: thread = unit tid, 16 batches
            const unsigned long long* src =
                hg + (size_t)(((si - 1) & 1) * 2 + dir) * 4096;
            const unsigned want = (unsigned)si;
            unsigned long long v[16];
            #pragma unroll
            for (int j = 0; j < 16; ++j)
                v[j] = __hip_atomic_load(&src[tid + 256 * j], __ATOMIC_RELAXED,
                                         __HIP_MEMORY_SCOPE_AGENT);
            bool any;
            do {
                any = false;
                #pragma unroll
                for (int j = 0; j < 16; ++j) {
                    if ((unsigned)(v[j] >> 32) != want) {
                        v[j] = __hip_atomic_load(&src[tid + 256 * j], __ATOMIC_RELAXED,
                                                 __HIP_MEMORY_SCOPE_AGENT);
                        if ((unsigned)(v[j] >> 32) != want) any = true;
                    }
                }
            } while (any);
            #pragma unroll
            for (int j = 0; j < 16; ++j) {
                unsigned d = (unsigned)v[j];
                hh[j * 264 + tid] = (unsigned short)(d & 0xffff);
                hl[j * 264 + tid] = (unsigned short)(d >> 16);
            }
            __syncthreads();
        }

        // ---- MFMA: this wave's gate for 16 batches x 16 units
        f32x4 acc = (f32x4){0.f, 0.f, 0.f, 0.f};
        #pragma unroll
        for (int kt = 0; kt < 8; ++kt) {
            const char* hp = (const char*)hh + lr * 528 + kt * 64 + lk * 16;
            const char* lp = (const char*)hl + lr * 528 + kt * 64 + lk * 16;
            bf16x8 ah = *(const bf16x8*)hp;
            bf16x8 al = *(const bf16x8*)lp;
            acc = __builtin_amdgcn_mfma_f32_16x16x32_bf16(ah, wfh[kt], acc, 0, 0, 0);
            acc = __builtin_amdgcn_mfma_f32_16x16x32_bf16(al, wfh[kt], acc, 0, 0, 0);
            acc = __builtin_amdgcn_mfma_f32_16x16x32_bf16(ah, wfl[kt], acc, 0, 0, 0);
        }
        #pragma unroll
        for (int i = 0; i < 4; ++i) gx[wv][lk * 4 + i][lr] = acc[i];
        __syncthreads();

        // ---- elementwise LSTM update for (eb, slice*16+eu)
        float ai = gx[0][eb][eu] + pi;
        float af = gx[1][eb][eu] + pf;
        float ag = gx[2][eb][eu] + pg;
        float ao = gx[3][eb][eu] + po;
        float gi = 1.0f / (1.0f + expf(-ai));
        float gf = 1.0f / (1.0f + expf(-af));
        float gg = tanhf(ag);
        float go = 1.0f / (1.0f + expf(-ao));
        c = gf * c + gi * gg;
        float h = go * tanhf(c);

        unsigned short h16 = f2bf(h);
        unsigned short l16 = f2bf(h - bf2f(h16));
        unsigned long long vpack =
            (unsigned long long)((unsigned)h16 | ((unsigned)l16 << 16)) |
            ((unsigned long long)(unsigned)(si + 1) << 32);
        unsigned long long* dst = hg + (size_t)((si & 1) * 2 + dir) * 4096;
        __hip_atomic_store(&dst[eb * 256 + slice * 16 + eu], vpack,
                           __ATOMIC_RELAXED, __HIP_MEMORY_SCOPE_AGENT);

        // feature stores: plain, off the critical path entirely
        size_t oi = ((size_t)(eb * NS + s)) * 512 + dir * 256 + slice * 16 + eu;
        fhi[oi] = h16;
        flo[oi] = l16;
    }
}

// ---------------------------------------------------------------------------
// In-place split softmax: row of N fp32 -> same memory becomes
// [N hi bf16][N lo bf16]. grid = rows, block = 256, N in {256, 1024}.
// ---------------------------------------------------------------------------
__global__ __launch_bounds__(256) void softmax_ip(float* __restrict__ X, int N)
{
    float* row = X + (size_t)blockIdx.x * N;
    unsigned short* o = (unsigned short*)row;
    int t = threadIdx.x;
    int cnt = N >> 8;
    float v[4];
    float m = -1e30f;
    for (int i = 0; i < cnt; ++i) { v[i] = row[t + (i << 8)]; m = fmaxf(m, v[i]); }
    for (int sh = 32; sh; sh >>= 1) m = fmaxf(m, __shfl_xor(m, sh));
    __shared__ float lm[4];
    if ((t & 63) == 0) lm[t >> 6] = m;
    __syncthreads();
    m = fmaxf(fmaxf(lm[0], lm[1]), fmaxf(lm[2], lm[3]));
    float s = 0.0f;
    for (int i = 0; i < cnt; ++i) { v[i] = expf(v[i] - m); s += v[i]; }
    for (int sh = 32; sh; sh >>= 1) s += __shfl_xor(s, sh);
    __shared__ float ls[4];
    if ((t & 63) == 0) ls[t >> 6] = s;
    __syncthreads();
    s = ls[0] + ls[1] + ls[2] + ls[3];
    float inv = 1.0f / s;
    __syncthreads();
    for (int i = 0; i < cnt; ++i) {
        float y = v[i] * inv;
        unsigned short h = f2bf(y);
        int j = t + (i << 8);
        o[j] = h;
        o[N + j] = f2bf(y - bf2f(h));
    }
}

// ---------------------------------------------------------------------------
// LayerNorm rows of 512 fp32 -> split bf16 out. grid = rows, block = 256.
// ---------------------------------------------------------------------------
__global__ __launch_bounds__(256) void layernorm_split(
    const float* __restrict__ X, const float* __restrict__ g, const float* __restrict__ b,
    unsigned short* __restrict__ ohi, unsigned short* __restrict__ olo)
{
    const float* row = X + (size_t)blockIdx.x * 512;
    size_t ob = (size_t)blockIdx.x * 512;
    int t = threadIdx.x;
    float x0 = row[t], x1 = row[t + 256];
    float s = x0 + x1, sq = x0 * x0 + x1 * x1;
    for (int o = 32; o; o >>= 1) { s += __shfl_xor(s, o); sq += __shfl_xor(sq, o); }
    __shared__ float ls[8];
    int w = t >> 6;
    if ((t & 63) == 0) { ls[w] = s; ls[4 + w] = sq; }
    __syncthreads();
    s = ls[0] + ls[1] + ls[2] + ls[3];
    sq = ls[4] + ls[5] + ls[6] + ls[7];
    float mu = s * (1.0f / 512.0f);
    float var = sq * (1.0f / 512.0f) - mu * mu;
    float inv = rsqrtf(var + 1e-5f);
    float y0 = (x0 - mu) * inv * g[t]       + b[t];
    float y1 = (x1 - mu) * inv * g[t + 256] + b[t + 256];
    unsigned short h0 = f2bf(y0), h1 = f2bf(y1);
    ohi[ob + t]       = h0;  olo[ob + t]       = f2bf(y0 - bf2f(h0));
    ohi[ob + t + 256] = h1;  olo[ob + t + 256] = f2bf(y1 - bf2f(h1));
}

// ---------------------------------------------------------------------------
// out[b,h] = dot(q[b,h,:], projT[h,:]) with hi+lo reconstruction
// ---------------------------------------------------------------------------
__global__ __launch_bounds__(256) void outproj3(
    const unsigned short* __restrict__ qhi, const unsigned short* __restrict__ qlo,
    const unsigned short* __restrict__ phi, const unsigned short* __restrict__ plo,
    float* __restrict__ out)
{
    int gw = blockIdx.x * 4 + (threadIdx.x >> 6);
    int lane = threadIdx.x & 63;
    int h = gw & 1023;
    uint4 qh = ((const uint4*)(qhi + (size_t)gw * 512))[lane];
    uint4 ql = ((const uint4*)(qlo + (size_t)gw * 512))[lane];
    uint4 ph = ((const uint4*)(phi + (size_t)h * 512))[lane];
    uint4 pl = ((const uint4*)(plo + (size_t)h * 512))[lane];
    unsigned short qhe[8], qle[8], phe[8], ple[8];
    *(uint4*)qhe = qh; *(uint4*)qle = ql; *(uint4*)phe = ph; *(uint4*)ple = pl;
    float s = 0.0f;
    #pragma unroll
    for (int i = 0; i < 8; ++i) {
        float q = bf2f(qhe[i]) + bf2f(qle[i]);
        float p = bf2f(phe[i]) + bf2f(ple[i]);
        s += q * p;
    }
    for (int o = 32; o; o >>= 1) s += __shfl_xor(s, o);
    if (lane == 0) out[gw] = s;
}

// ---------------------------------------------------------------------------
// launcher
// ---------------------------------------------------------------------------
extern "C" void kernel_launch(void* const* d_in, const int* in_sizes, int n_in,
                              void* d_out, int out_size, void* d_ws, size_t ws_size,
                              hipStream_t stream)
{
    (void)in_sizes; (void)n_in; (void)out_size; (void)ws_size;

    const float* x     = (const float*)d_in[0];
    const float* le    = (const float*)d_in[1];
    const float* proj  = (const float*)d_in[2];
    const float* WihF  = (const float*)d_in[3];
    const float* WhhF  = (const float*)d_in[4];
    const float* bihF  = (const float*)d_in[5];
    const float* bhhF  = (const float*)d_in[6];
    const float* WihB  = (const float*)d_in[7];
    const float* WhhB  = (const float*)d_in[8];
    const float* bihB  = (const float*)d_in[9];
    const float* bhhB  = (const float*)d_in[10];
    const float* w1    = (const float*)d_in[11];
    const float* b1    = (const float*)d_in[12];
    const float* w2    = (const float*)d_in[13];
    const float* b2    = (const float*)d_in[14];
    const float* lng   = (const float*)d_in[15];
    const float* lnb   = (const float*)d_in[16];
    float* out = (float*)d_out;
    float* ws  = (float*)d_ws;
    unsigned short* wsu = (unsigned short*)d_ws;

    const size_t MEG = 1048576;
    // float-offset layout (~50M floats = 200 MB)
    const size_t R0    = 0;              // 8M: pre (4096x2048) -> qt-split (L1) -> lnsrc
    const size_t R1    = 8 * MEG;        // 8M: q2 split
    const size_t AR    = 16 * MEG;       // 17M arena
    const size_t QHI   = 33 * MEG;       // 4M each
    const size_t QLO   = 37 * MEG;
    const size_t FHI   = 41 * MEG;       // 1M each
    const size_t FLO   = 42 * MEG;
    const size_t FTHI  = 43 * MEG;
    const size_t FTLO  = 44 * MEG;
    const size_t LEHI  = 45 * MEG;
    const size_t LELO  = LEHI  + MEG / 4;
    const size_t LETHI = LELO  + MEG / 4;
    const size_t LETLO = LETHI + MEG / 4;
    const size_t WIHH  = 46 * MEG;       // 1M u16 (= MEG/2 fl)
    const size_t WIHL  = WIHH + MEG / 2;
    const size_t SYNC  = 47 * MEG;       // hg: 16384 u64 = 128KB
    const size_t W1TH  = SYNC  + MEG / 4;
    const size_t W1TL  = W1TH  + MEG / 2;
    const size_t W2TH  = W1TL  + MEG / 2;
    const size_t W2TL  = W2TH  + MEG / 2;
    const size_t PTH   = W2TL  + MEG / 2;
    const size_t PTL   = PTH   + MEG / 4;
    const size_t BSUM  = PTL   + MEG / 4;

    float* pre    = ws + R0;             // (4096, 2048): [F 1024 | B 1024]
    float* lnsrc  = ws + R0;
    float* arena  = ws + AR;
    float* bsum   = ws + BSUM;
    unsigned long long* hg = (unsigned long long*)(ws + SYNC);
    unsigned short* qthi  = wsu + 2 * R0;
    unsigned short* qtlo  = wsu + 2 * (R0 + 4 * MEG);
    unsigned short* q2hi  = wsu + 2 * R1;
    unsigned short* q2lo  = wsu + 2 * (R1 + 4 * MEG);
    unsigned short* qhi   = wsu + 2 * QHI;
    unsigned short* qlo   = wsu + 2 * QLO;
    unsigned short* fhi   = wsu + 2 * FHI;
    unsigned short* flo   = wsu + 2 * FLO;
    unsigned short* fthi  = wsu + 2 * FTHI;
    unsigned short* ftlo  = wsu + 2 * FTLO;
    unsigned short* lehi  = wsu + 2 * LEHI;
    unsigned short* lelo  = wsu + 2 * LELO;
    unsigned short* lethi = wsu + 2 * LETHI;
    unsigned short* letlo = wsu + 2 * LETLO;
    unsigned short* wihh  = wsu + 2 * WIHH;       // [F rows 0..1023 | B rows 1024..2047] x 512
    unsigned short* wihl  = wsu + 2 * WIHL;
    unsigned short* w1th  = wsu + 2 * W1TH;
    unsigned short* w1tl  = wsu + 2 * W1TL;
    unsigned short* w2th  = wsu + 2 * W2TH;
    unsigned short* w2tl  = wsu + 2 * W2TL;
    unsigned short* pth   = wsu + 2 * PTH;
    unsigned short* ptl   = wsu + 2 * PTL;

    // ---- prep
    bias_sum_kernel<<<8, 256, 0, stream>>>(bihF, bhhF, bihB, bhhB, bsum);
    cvt_split<<<512, 256, 0, stream>>>(WihF, wihh, wihl);
    cvt_split<<<512, 256, 0, stream>>>(WihB, wihh + 524288, wihl + 524288);
    cvt_split<<<512, 256, 0, stream>>>(le, lehi, lelo);
    { dim3 g(512 / 64, 1024 / 64, 1);
      tcvt_bf16<<<g, 256, 0, stream>>>(lehi, lethi, 1024, 512);
      tcvt_bf16<<<g, 256, 0, stream>>>(lelo, letlo, 1024, 512); }
    hipMemsetAsync(hg, 0, 16384 * sizeof(unsigned long long), stream);

    // x -> split (arena scratch)
    unsigned short* xhi = wsu + 2 * AR;
    unsigned short* xlo = wsu + 2 * (AR + MEG);
    cvt_split<<<2048, 256, 0, stream>>>(x, xhi, xlo);

    // ---- LSTM input projection (merged F|B): pre = x @ [WihF;WihB]^T + bsum
    gemm_f(0, xhi, xlo, wihh, wihl, bsum, pre, NB * NS, 2048, ND, ND, ND, 0, 0, 0, 1, stream);

    // ---- recurrence -> features (split bf16), tagged-exchange kernel
    lstm_rec8<<<32, 256, 0, stream>>>(pre, WhhF, WhhB, hg, fhi, flo);
    { dim3 g(512 / 64, 256 / 64, 16);
      tcvt_bf16<<<g, 256, 0, stream>>>(fhi, fthi, 256, 512);
      tcvt_bf16<<<g, 256, 0, stream>>>(flo, ftlo, 256, 512); }

    // ---- layers
    for (int l = 0; l < 2; ++l) {
        const float* b1l = b1 + (size_t)l * NF;
        const float* b2l = b2 + (size_t)l * ND;
        const float* gl  = lng + (size_t)l * ND;
        const float* bl  = lnb + (size_t)l * ND;

        // FFN weights -> split bf16, transposed (tmp in arena)
        unsigned short* wth = wsu + 2 * (AR + 2 * MEG);
        unsigned short* wtl = wsu + 2 * (AR + 2 * MEG + MEG / 2);
        cvt_split<<<1024, 256, 0, stream>>>(w1 + (size_t)l * ND * NF, wth, wtl);
        { dim3 g(NF / 64, ND / 64, 1);
          tcvt_bf16<<<g, 256, 0, stream>>>(wth, w1th, ND, NF);
          tcvt_bf16<<<g, 256, 0, stream>>>(wtl, w1tl, ND, NF); }
        cvt_split<<<1024, 256, 0, stream>>>(w2 + (size_t)l * NF * ND, wth, wtl);
        { dim3 g(ND / 64, NF / 64, 1);
          tcvt_bf16<<<g, 256, 0, stream>>>(wth, w2th, NF, ND);
          tcvt_bf16<<<g, 256, 0, stream>>>(wtl, w2tl, NF, ND); }

        if (l == 0) {
            float* wsc = arena;
            unsigned short* wscu = (unsigned short*)wsc;
            unsigned short* q1hi = wsu + 2 * (AR + 1 * MEG);
            unsigned short* q1lo = wsu + 2 * (AR + 1 * MEG + MEG / 4);
            float* s2s = arena + 4 * MEG;
            unsigned short* s2u = (unsigned short*)s2s;

            gemm_f(0, lehi, lelo, lehi, lelo, nullptr, wsc, NH, NH, ND, ND, ND, 0, 0, 0, 1, stream);
            softmax_ip<<<NH, 256, 0, stream>>>(wsc, NH);
            gemm_s(0, wscu, wscu + NH, lethi, letlo, nullptr, q1hi, q1lo,
                   NH, ND, NH, 2 * NH, NH, 0, 0, 0, 1, stream);
            gemm_f(0, q1hi, q1lo, fhi, flo, nullptr, s2s, NH, NS, ND, ND, ND,
                   0, (long)NS * ND, (long)NH * NS, 16, stream);
            softmax_ip<<<NB * NH, 256, 0, stream>>>(s2s, NS);
            gemm_s(0, s2u, s2u + NS, fthi, ftlo, nullptr, q2hi, q2lo,
                   NH, ND, NS, 2 * NS, NS,
                   (long)2 * NH * NS, (long)ND * NS, (long)NH * ND, 16, stream);
        } else {
            { dim3 g(512 / 64, 1024 / 64, 16);
              tcvt_bf16<<<g, 256, 0, stream>>>(qhi, qthi, 1024, 512);
              tcvt_bf16<<<g, 256, 0, stream>>>(qlo, qtlo, 1024, 512); }
            float* wsc = arena;
            unsigned short* wscu = (unsigned short*)wsc;
            unsigned short* q1hi = wsu + 2 * (AR + 8 * MEG);
            unsigned short* q1lo = wsu + 2 * (AR + 10 * MEG);
            float* s2s = arena + 12 * MEG;
            unsigned short* s2u = (unsigned short*)s2s;
            for (int g8 = 0; g8 < 2; ++g8) {
                size_t qo = (size_t)g8 * 8;
                gemm_f(0, qhi + qo * NH * ND, qlo + qo * NH * ND,
                       qhi + qo * NH * ND, qlo + qo * NH * ND, nullptr, wsc,
                       NH, NH, ND, ND, ND,
                       (long)NH * ND, (long)NH * ND, (long)NH * NH, 8, stream);
                softmax_ip<<<8 * NH, 256, 0, stream>>>(wsc, NH);
                gemm_s(0, wscu, wscu + NH, qthi + qo * ND * NH, qtlo + qo * ND * NH,
                       nullptr, q1hi, q1lo, NH, ND, NH, 2 * NH, NH,
                       (long)2 * NH * NH, (long)ND * NH, (long)NH * ND, 8, stream);
                gemm_f(0, q1hi, q1lo, fhi + qo * NS * ND, flo + qo * NS * ND,
                       nullptr, s2s, NH, NS, ND, ND, ND,
                       (long)NH * ND, (long)NS * ND, (long)NH * NS, 8, stream);
                softmax_ip<<<8 * NH, 256, 0, stream>>>(s2s, NS);
                gemm_s(0, s2u, s2u + NS, fthi + qo * ND * NS, ftlo + qo * ND * NS,
                       nullptr, q2hi + qo * NH * ND, q2lo + qo * NH * ND,
                       NH, ND, NS, 2 * NS, NS,
                       (long)2 * NH * NS, (long)ND * NS, (long)NH * ND, 8, stream);
            }
        }

        // FFN: 2 chunks of 8192 rows
        unsigned short* ffhi = wsu + 2 * AR;
        unsigned short* fflo = wsu + 2 * (AR + 8 * MEG);
        for (int ch = 0; ch < 2; ++ch) {
            const unsigned short* rih = q2hi + (size_t)ch * 8192 * ND;
            const unsigned short* ril = q2lo + (size_t)ch * 8192 * ND;
            float* rows_out = lnsrc + (size_t)ch * 8192 * ND;
            gemm_s(1, rih, ril, w1th, w1tl, b1l, ffhi, fflo,
                   8192, NF, ND, ND, ND, 0, 0, 0, 1, stream);
            gemm_f(0, ffhi, fflo, w2th, w2tl, b2l, rows_out,
                   8192, ND, NF, NF, NF, 0, 0, 0, 1, stream);
        }
        layernorm_split<<<NB * NH, 256, 0, stream>>>(lnsrc, gl, bl, qhi, qlo);
    }

    // ---- final projection
    {
        unsigned short* prh = wsu + 2 * AR;
        unsigned short* prl = wsu + 2 * (AR + MEG / 4);
        cvt_split<<<512, 256, 0, stream>>>(proj, prh, prl);
        dim3 g(1024 / 64, 512 / 64, 1);
        tcvt_bf16<<<g, 256, 0, stream>>>(prh, pth, 512, 1024);
        tcvt_bf16<<<g, 256, 0, stream>>>(prl, ptl, 512, 1024);
    }
    outproj3<<<4096, 256, 0, stream>>>(qhi, qlo, pth, ptl, out);
}